// Round 1
// baseline (79309.119 us; speedup 1.0000x reference)
//
#include <hip/hip_runtime.h>
#include <hip/hip_bf16.h>
#include <stdint.h>

// ============================================================================
// DaleConstrainedIntegrator: s_t = mask*clip((s_{t-1}+mask*ext_t) @ Weff^T),
// o0/o1 = dec{0,1}·s_t.  N=2048, B=128, T=1024.
//
// Design:
//  * ONE persistent kernel, grid=256 WGs x 512 thr (1 WG/CU, 8 waves).
//  * WG (p,q) owns output tile [32 batches x 32 neurons]; p in 0..3, q in 0..63.
//  * Weff slice (32 rows x 2048 cols, bf16, signs folded) lives in LDS for the
//    WHOLE run (128 KB), XOR-slot swizzle -> conflict-free ds_read_b128 B-frags.
//  * State+input vector I_t kept in ws as frag-packed bf16 (double buffered):
//    I[par][p][kt][lane][e]  == A-fragment order of v_mfma_f32_32x32x16_bf16
//    (A row = lane&31, k = kt*16 + (lane>>5)*8 + e). A-frag = 1 dwordx4/lane.
//  * 8 waves split K (each 16 kt of 16), LDS tree reduce, wave0 applies
//    clip/mask; epilogue (all 512 thr) does dec-dot partials (atomicAdd into
//    d_out) and writes I_{t+1} = ns + mask*(enc0*x0[t+1]+enc1*x1[t+1]).
//  * Sync: 4 independent 64-WG barrier groups (only WGs sharing p interact),
//    LLC-scope atomics + threadfence release/acquire => correct for ANY
//    WG->XCD placement. Bounded spin guard avoids harness hangs.
// ============================================================================

#define NN 2048
#define BB 128
#define TT 1024

typedef __attribute__((ext_vector_type(8)))  __bf16          bf16x8;
typedef __attribute__((ext_vector_type(8)))  unsigned short  ushort8;
typedef __attribute__((ext_vector_type(16))) float           f32x16;

// ws layout (bytes)
#define IF_OFF   0u              // ushort I[2][4][128][64][8] = 1 MB
#define IF_FRAGS 32768           // bf16x8 frags per parity (4*128*64)
#define CTR_OFF  (1u << 20)      // uint ctr[1024][4][16] (64B padded) = 256 KB
#define CTR_BYTES (1024u * 4u * 16u * 4u)

__device__ __forceinline__ unsigned short f2bf(float f) {
    __hip_bfloat16 h = __float2bfloat16(f);
    return *reinterpret_cast<unsigned short*>(&h);
}

// ---------------------------------------------------------------------------
// Build I_0 = state0 + mask*(enc0*x0[:,0] + enc1*x1[:,0]), frag-packed.
// ---------------------------------------------------------------------------
__global__ void init_pack(const float* __restrict__ x0, const float* __restrict__ x1,
                          const float* __restrict__ enc0, const float* __restrict__ enc1,
                          const float* __restrict__ mask, const float* __restrict__ state0,
                          unsigned short* __restrict__ If)
{
    int idx  = blockIdx.x * 256 + threadIdx.x;        // 0 .. 262143
    int e    = idx & 7;
    int lane = (idx >> 3) & 63;
    int kt   = (idx >> 9) & 127;
    int p    = idx >> 16;
    int b    = p * 32 + (lane & 31);
    int j    = kt * 16 + ((lane >> 5) << 3) + e;
    float v  = state0[j] + mask[j] * (enc0[j] * x0[(size_t)b * TT]
                                    + enc1[j] * x1[(size_t)b * TT]);
    If[idx] = f2bf(v);
}

// ---------------------------------------------------------------------------
// Persistent recurrence kernel.
// Dynamic LDS blob:
//   [0,128K)           Wl   : swizzled bf16 [32][2048]
//   [128K, +17408)     red  : float[4][64][17]   (K-split tree reduce)
//   [.. , +4352)       nsbuf: float[32][34]      (new-state tile)
//   [.. , +768)        ldsC : float[6][32]       mask,dec0,dec1,enc0,enc1
//   [.. , +256)        xbuf : float[2][32]       x0,x1 at t+1 for our batches
// total 153856 B
// ---------------------------------------------------------------------------
#define LDS_TOTAL 153856

__global__ void __launch_bounds__(512, 2)
dale_persistent(const float* __restrict__ x0, const float* __restrict__ x1,
                const float* __restrict__ enc0, const float* __restrict__ enc1,
                const float* __restrict__ dec0, const float* __restrict__ dec1,
                const float* __restrict__ W, const float* __restrict__ signs,
                const float* __restrict__ mask,
                unsigned short* __restrict__ If,
                unsigned int* __restrict__ ctr,
                float* __restrict__ out)
{
    extern __shared__ char lds[];
    float* red   = reinterpret_cast<float*>(lds + 131072);
    float* nsbuf = reinterpret_cast<float*>(lds + 131072 + 17408);
    float* ldsC  = reinterpret_cast<float*>(lds + 131072 + 17408 + 4352);
    float* xbuf  = reinterpret_cast<float*>(lds + 131072 + 17408 + 4352 + 768);

    const int tid  = threadIdx.x;
    const int wave = tid >> 6;
    const int lane = tid & 63;
    const int wg   = blockIdx.x;
    // placement: p-group (64 WGs) lands on an XCD pair; q gives W slice.
    const int p  = (wg & 7) >> 1;                  // 0..3  batch chunk
    const int q  = ((wg & 1) << 5) | (wg >> 3);    // 0..63 neuron chunk
    const int b0 = p * 32;
    const int i0 = q * 32;

    // ---- one-time: Weff slice -> LDS (bf16, signs folded, slot-swizzled)
    // octet o: row il = o>>8 (0..31), k-octet k8 = o&255. slot = k8 ^ il.
    for (int o = tid; o < 8192; o += 512) {
        int il = o >> 8;
        int k8 = o & 255;
        const float* wr = W + (size_t)(i0 + il) * NN + k8 * 8;
        const float* sg = signs + k8 * 8;
        ushort8 pk;
        #pragma unroll
        for (int e = 0; e < 8; ++e) pk[e] = f2bf(wr[e] * sg[e]);
        int slot = k8 ^ il;
        *reinterpret_cast<ushort8*>(lds + il * 4096 + slot * 16) = pk;
    }
    if (tid < 32) {
        ldsC[tid]       = mask[i0 + tid];
        ldsC[32 + tid]  = dec0[i0 + tid];
        ldsC[64 + tid]  = dec1[i0 + tid];
        ldsC[96 + tid]  = enc0[i0 + tid];
        ldsC[128 + tid] = enc1[i0 + tid];
    }
    __syncthreads();

    const bf16x8* Ifrag = reinterpret_cast<const bf16x8*>(If);
    const int il = lane & 31;      // A row (batch) / B col's W-row (neuron)
    const int hi = lane >> 5;

    for (int t = 0; t < TT; ++t) {
        const int par = t & 1;

        // prefetch x(t+1) for our 32 batches
        if (tid < 64) {
            int bb = tid & 31;
            const float* xs = (tid < 32) ? x0 : x1;
            float v = (t + 1 < TT) ? xs[(size_t)(b0 + bb) * TT + (t + 1)] : 0.f;
            xbuf[(tid >> 5) * 32 + bb] = v;
        }

        // ---- MFMA: wave handles kt = wave*16 .. +16 (K-split)
        f32x16 acc;
        #pragma unroll
        for (int r = 0; r < 16; ++r) acc[r] = 0.f;
        const bf16x8* ap = Ifrag + (size_t)par * IF_FRAGS
                         + (p * 128 + wave * 16) * 64 + lane;
        char* wrow = lds + il * 4096;
        #pragma unroll 8
        for (int it = 0; it < 16; ++it) {
            int kt   = wave * 16 + it;
            bf16x8 a = ap[it * 64];
            int slot = (kt * 2 + hi) ^ il;
            bf16x8 b = *reinterpret_cast<const bf16x8*>(wrow + slot * 16);
            acc = __builtin_amdgcn_mfma_f32_32x32x16_bf16(a, b, acc, 0, 0, 0);
        }

        // ---- tree reduce 8 waves -> wave0 (red[4][64][17])
        if (wave >= 4) {
            float* d = red + (wave - 4) * 1088 + lane * 17;
            #pragma unroll
            for (int r = 0; r < 16; ++r) d[r] = acc[r];
        }
        __syncthreads();
        if (wave < 4) {
            const float* s = red + wave * 1088 + lane * 17;
            #pragma unroll
            for (int r = 0; r < 16; ++r) acc[r] += s[r];
        }
        __syncthreads();
        if (wave == 2 || wave == 3) {
            float* d = red + (wave - 2) * 1088 + lane * 17;
            #pragma unroll
            for (int r = 0; r < 16; ++r) d[r] = acc[r];
        }
        __syncthreads();
        if (wave < 2) {
            const float* s = red + wave * 1088 + lane * 17;
            #pragma unroll
            for (int r = 0; r < 16; ++r) acc[r] += s[r];
        }
        __syncthreads();
        if (wave == 1) {
            float* d = red + lane * 17;
            #pragma unroll
            for (int r = 0; r < 16; ++r) d[r] = acc[r];
        }
        __syncthreads();
        if (wave == 0) {
            const float* s = red + lane * 17;
            float mk = ldsC[il];
            #pragma unroll
            for (int r = 0; r < 16; ++r) {
                float raw  = acc[r] + s[r];
                int   brow = (r & 3) + 8 * (r >> 2) + 4 * hi;   // C/D layout (m74/m101)
                float ns   = fminf(fmaxf(raw, 0.f), 1e8f) * mk;
                nsbuf[brow * 34 + il] = ns;
            }
        }
        __syncthreads();

        // ---- epilogue: 512 thr, 2 elems each. eb=batch row, ei=col pair.
        {
            int eb = tid >> 4;
            int ei = (tid & 15) * 2;
            float ns0 = nsbuf[eb * 34 + ei];
            float ns1 = nsbuf[eb * 34 + ei + 1];
            float o0p = ldsC[32 + ei] * ns0 + ldsC[32 + ei + 1] * ns1;
            float o1p = ldsC[64 + ei] * ns0 + ldsC[64 + ei + 1] * ns1;
            #pragma unroll
            for (int m = 8; m >= 1; m >>= 1) {
                o0p += __shfl_xor(o0p, m);
                o1p += __shfl_xor(o1p, m);
            }
            if ((tid & 15) == 0) {
                atomicAdd(out + (size_t)(b0 + eb) * TT + t, o0p);
                atomicAdd(out + (size_t)BB * TT + (size_t)(b0 + eb) * TT + t, o1p);
            }
            if (t + 1 < TT) {
                float xb0 = xbuf[eb], xb1 = xbuf[32 + eb];
                float v0 = ns0 + ldsC[ei]     * (ldsC[96 + ei]     * xb0 + ldsC[128 + ei]     * xb1);
                float v1 = ns1 + ldsC[ei + 1] * (ldsC[96 + ei + 1] * xb0 + ldsC[128 + ei + 1] * xb1);
                int j0 = i0 + ei;
                int kt = j0 >> 4, hb = (j0 >> 3) & 1, e = j0 & 7;
                int fl = eb | (hb << 5);
                unsigned int packed = (unsigned int)f2bf(v0)
                                    | ((unsigned int)f2bf(v1) << 16);
                unsigned int* dst = reinterpret_cast<unsigned int*>(If)
                    + ((((unsigned)(1 - par)) * IF_FRAGS + (p * 128 + kt) * 64 + fl) * 8 + e) / 2;
                *dst = packed;
            }
        }

        // ---- p-group barrier (64 WGs), device-correct for any placement
        __syncthreads();
        __threadfence();            // release: our I_{t+1} stores visible
        __syncthreads();
        if (tid == 0) {
            unsigned int* cp = ctr + ((unsigned)t * 4u + (unsigned)p) * 16u;
            __hip_atomic_fetch_add(cp, 1u, __ATOMIC_RELEASE, __HIP_MEMORY_SCOPE_AGENT);
            int guard = 0;
            while (__hip_atomic_load(cp, __ATOMIC_ACQUIRE, __HIP_MEMORY_SCOPE_AGENT) < 64u
                   && ++guard < (1 << 18)) {
                __builtin_amdgcn_s_sleep(2);
            }
        }
        __syncthreads();
        __threadfence();            // acquire: invalidate stale cached I lines
    }
}

// ---------------------------------------------------------------------------
extern "C" void kernel_launch(void* const* d_in, const int* in_sizes, int n_in,
                              void* d_out, int out_size, void* d_ws, size_t ws_size,
                              hipStream_t stream)
{
    (void)in_sizes; (void)n_in; (void)ws_size;
    const float* x0    = (const float*)d_in[0];
    const float* x1    = (const float*)d_in[1];
    const float* enc0  = (const float*)d_in[2];
    const float* enc1  = (const float*)d_in[3];
    const float* dec0  = (const float*)d_in[4];
    const float* dec1  = (const float*)d_in[5];
    const float* W     = (const float*)d_in[6];
    const float* signs = (const float*)d_in[7];
    const float* mask  = (const float*)d_in[8];
    const float* st0   = (const float*)d_in[9];

    unsigned short* If  = (unsigned short*)((char*)d_ws + IF_OFF);
    unsigned int*   ctr = (unsigned int*)((char*)d_ws + CTR_OFF);
    float*          out = (float*)d_out;

    hipMemsetAsync(d_out, 0, sizeof(float) * (size_t)out_size, stream);
    hipMemsetAsync(ctr, 0, CTR_BYTES, stream);

    init_pack<<<1024, 256, 0, stream>>>(x0, x1, enc0, enc1, mask, st0, If);

    hipFuncSetAttribute(reinterpret_cast<const void*>(&dale_persistent),
                        hipFuncAttributeMaxDynamicSharedMemorySize, LDS_TOTAL);
    dale_persistent<<<256, 512, LDS_TOTAL, stream>>>(
        x0, x1, enc0, enc1, dec0, dec1, W, signs, mask, If, ctr, out);
}

// Round 2
// 7144.142 us; speedup vs baseline: 11.1013x; 11.1013x over previous
//
#include <hip/hip_runtime.h>
#include <hip/hip_bf16.h>
#include <stdint.h>

// ============================================================================
// DaleConstrainedIntegrator: s_t = mask*clip((s_{t-1}+mask*ext_t) @ Weff^T),
// o0/o1 = dec{0,1}·s_t.  N=2048, B=128, T=1024.
//
// R2 change vs R1: __threadfence() (full per-XCD L2 writeback/invalidate,
// ~100us/step measured) is ELIMINATED. Cross-WG coherence is now per-access:
//   * state fragments written with  global_store_dword  ... sc0 sc1 (LLC
//     write-through, bypass non-coherent L2)
//   * state fragments read with     global_load_dwordx4 ... sc0 sc1 (read
//     from LLC, bypass possibly-stale own L2)
//   * barrier: per-wave s_waitcnt vmcnt(0) -> __syncthreads -> RELAXED
//     agent-scope atomic arrive -> RELAXED poll (no acquire fence => no
//     buffer_inv). Output atomicAdds issued AFTER arrive (fire-and-forget).
// Everything else (tiling, fragment layouts, reduce tree) is identical to the
// R1 kernel that validated at absmax 5.7e-6.
// ============================================================================

#define NN 2048
#define BB 128
#define TT 1024

typedef __attribute__((ext_vector_type(8)))  __bf16          bf16x8;
typedef __attribute__((ext_vector_type(8)))  unsigned short  ushort8;
typedef __attribute__((ext_vector_type(16))) float           f32x16;

// ws layout (bytes)
#define IF_OFF   0u              // ushort I[2][4][128][64][8] = 1 MB
#define IF_FRAGS 32768           // bf16x8 frags per parity (4*128*64)
#define CTR_OFF  (1u << 20)      // uint ctr[1024][4][16] (64B padded) = 256 KB
#define CTR_BYTES (1024u * 4u * 16u * 4u)

__device__ __forceinline__ unsigned short f2bf(float f) {
    __hip_bfloat16 h = __float2bfloat16(f);
    return *reinterpret_cast<unsigned short*>(&h);
}

// ---------------------------------------------------------------------------
// Build I_0 = state0 + mask*(enc0*x0[:,0] + enc1*x1[:,0]), frag-packed.
// (Separate dispatch: kernel-boundary release flushes L2 -> LLC, so the
//  persistent kernel's sc1 loads see this data.)
// ---------------------------------------------------------------------------
__global__ void init_pack(const float* __restrict__ x0, const float* __restrict__ x1,
                          const float* __restrict__ enc0, const float* __restrict__ enc1,
                          const float* __restrict__ mask, const float* __restrict__ state0,
                          unsigned short* __restrict__ If)
{
    int idx  = blockIdx.x * 256 + threadIdx.x;        // 0 .. 262143
    int e    = idx & 7;
    int lane = (idx >> 3) & 63;
    int kt   = (idx >> 9) & 127;
    int p    = idx >> 16;
    int b    = p * 32 + (lane & 31);
    int j    = kt * 16 + ((lane >> 5) << 3) + e;
    float v  = state0[j] + mask[j] * (enc0[j] * x0[(size_t)b * TT]
                                    + enc1[j] * x1[(size_t)b * TT]);
    If[idx] = f2bf(v);
}

// ---------------------------------------------------------------------------
// Persistent recurrence kernel.
// Dynamic LDS blob:
//   [0,128K)           Wl   : swizzled bf16 [32][2048]
//   [128K, +17408)     red  : float[4][64][17]   (K-split tree reduce)
//   [.. , +4352)       nsbuf: float[32][34]      (new-state tile)
//   [.. , +768)        ldsC : float[6][32]       mask,dec0,dec1,enc0,enc1
//   [.. , +256)        xbuf : float[2][32]       x0,x1 at t+1 for our batches
// total 153856 B
// ---------------------------------------------------------------------------
#define LDS_TOTAL 153856

__global__ void __launch_bounds__(512, 2)
dale_persistent(const float* __restrict__ x0, const float* __restrict__ x1,
                const float* __restrict__ enc0, const float* __restrict__ enc1,
                const float* __restrict__ dec0, const float* __restrict__ dec1,
                const float* __restrict__ W, const float* __restrict__ signs,
                const float* __restrict__ mask,
                unsigned short* __restrict__ If,
                unsigned int* __restrict__ ctr,
                float* __restrict__ out)
{
    extern __shared__ char lds[];
    float* red   = reinterpret_cast<float*>(lds + 131072);
    float* nsbuf = reinterpret_cast<float*>(lds + 131072 + 17408);
    float* ldsC  = reinterpret_cast<float*>(lds + 131072 + 17408 + 4352);
    float* xbuf  = reinterpret_cast<float*>(lds + 131072 + 17408 + 4352 + 768);

    const int tid  = threadIdx.x;
    const int wave = tid >> 6;
    const int lane = tid & 63;
    const int wg   = blockIdx.x;
    const int p  = (wg & 7) >> 1;                  // 0..3  batch chunk
    const int q  = ((wg & 1) << 5) | (wg >> 3);    // 0..63 neuron chunk
    const int b0 = p * 32;
    const int i0 = q * 32;

    // ---- one-time: Weff slice -> LDS (bf16, signs folded, slot-swizzled)
    for (int o = tid; o < 8192; o += 512) {
        int il = o >> 8;
        int k8 = o & 255;
        const float* wr = W + (size_t)(i0 + il) * NN + k8 * 8;
        const float* sg = signs + k8 * 8;
        ushort8 pk;
        #pragma unroll
        for (int e = 0; e < 8; ++e) pk[e] = f2bf(wr[e] * sg[e]);
        int slot = k8 ^ il;
        *reinterpret_cast<ushort8*>(lds + il * 4096 + slot * 16) = pk;
    }
    if (tid < 32) {
        ldsC[tid]       = mask[i0 + tid];
        ldsC[32 + tid]  = dec0[i0 + tid];
        ldsC[64 + tid]  = dec1[i0 + tid];
        ldsC[96 + tid]  = enc0[i0 + tid];
        ldsC[128 + tid] = enc1[i0 + tid];
    }
    __syncthreads();

    const bf16x8* Ifrag = reinterpret_cast<const bf16x8*>(If);
    const int il = lane & 31;      // A row (batch) / B col's W-row (neuron)
    const int hi = lane >> 5;
    char* wrow = lds + il * 4096;

    for (int t = 0; t < TT; ++t) {
        const int par = t & 1;

        // ---- issue A-fragment loads FIRST (coherent, LLC-sourced; latency
        //      overlaps with x-prefetch + address math below)
        bf16x8 A[16];
        const bf16x8* ap = Ifrag + (size_t)par * IF_FRAGS
                         + (p * 128 + wave * 16) * 64 + lane;
        #pragma unroll
        for (int it = 0; it < 16; ++it) {
            const bf16x8* aptr = ap + it * 64;
            asm volatile("global_load_dwordx4 %0, %1, off sc0 sc1"
                         : "=v"(A[it]) : "v"(aptr) : "memory");
        }

        // prefetch x(t+1) for our 32 batches (read-only input: plain loads)
        if (tid < 64) {
            int bb = tid & 31;
            const float* xs = (tid < 32) ? x0 : x1;
            float v = (t + 1 < TT) ? xs[(size_t)(b0 + bb) * TT + (t + 1)] : 0.f;
            xbuf[(tid >> 5) * 32 + bb] = v;
        }

        // wait for inline-asm loads; fence the scheduler (rule #18)
        asm volatile("s_waitcnt vmcnt(0)" ::: "memory");
        __builtin_amdgcn_sched_barrier(0);

        // ---- MFMA: wave handles kt = wave*16 .. +16 (K-split)
        f32x16 acc;
        #pragma unroll
        for (int r = 0; r < 16; ++r) acc[r] = 0.f;
        #pragma unroll
        for (int it = 0; it < 16; ++it) {
            int kt   = wave * 16 + it;
            int slot = (kt * 2 + hi) ^ il;
            bf16x8 b = *reinterpret_cast<const bf16x8*>(wrow + slot * 16);
            acc = __builtin_amdgcn_mfma_f32_32x32x16_bf16(A[it], b, acc, 0, 0, 0);
        }

        // ---- tree reduce 8 waves -> wave0 (red[4][64][17])
        if (wave >= 4) {
            float* d = red + (wave - 4) * 1088 + lane * 17;
            #pragma unroll
            for (int r = 0; r < 16; ++r) d[r] = acc[r];
        }
        __syncthreads();
        if (wave < 4) {
            const float* s = red + wave * 1088 + lane * 17;
            #pragma unroll
            for (int r = 0; r < 16; ++r) acc[r] += s[r];
        }
        __syncthreads();
        if (wave == 2 || wave == 3) {
            float* d = red + (wave - 2) * 1088 + lane * 17;
            #pragma unroll
            for (int r = 0; r < 16; ++r) d[r] = acc[r];
        }
        __syncthreads();
        if (wave < 2) {
            const float* s = red + wave * 1088 + lane * 17;
            #pragma unroll
            for (int r = 0; r < 16; ++r) acc[r] += s[r];
        }
        __syncthreads();
        if (wave == 1) {
            float* d = red + lane * 17;
            #pragma unroll
            for (int r = 0; r < 16; ++r) d[r] = acc[r];
        }
        __syncthreads();
        if (wave == 0) {
            const float* s = red + lane * 17;
            float mk = ldsC[il];
            #pragma unroll
            for (int r = 0; r < 16; ++r) {
                float raw  = acc[r] + s[r];
                int   brow = (r & 3) + 8 * (r >> 2) + 4 * hi;   // C/D layout (m74/m101)
                float ns   = fminf(fmaxf(raw, 0.f), 1e8f) * mk;
                nsbuf[brow * 34 + il] = ns;
            }
        }
        __syncthreads();

        // ---- epilogue: 512 thr, 2 elems each. eb=batch row, ei=col pair.
        int eb = tid >> 4;
        int ei = (tid & 15) * 2;
        float ns0 = nsbuf[eb * 34 + ei];
        float ns1 = nsbuf[eb * 34 + ei + 1];
        float o0p = ldsC[32 + ei] * ns0 + ldsC[32 + ei + 1] * ns1;
        float o1p = ldsC[64 + ei] * ns0 + ldsC[64 + ei + 1] * ns1;
        #pragma unroll
        for (int m = 8; m >= 1; m >>= 1) {
            o0p += __shfl_xor(o0p, m);
            o1p += __shfl_xor(o1p, m);
        }
        if (t + 1 < TT) {
            float xb0 = xbuf[eb], xb1 = xbuf[32 + eb];
            float v0 = ns0 + ldsC[ei]     * (ldsC[96 + ei]     * xb0 + ldsC[128 + ei]     * xb1);
            float v1 = ns1 + ldsC[ei + 1] * (ldsC[96 + ei + 1] * xb0 + ldsC[128 + ei + 1] * xb1);
            int j0 = i0 + ei;
            int kt = j0 >> 4, hb = (j0 >> 3) & 1, e = j0 & 7;
            int fl = eb | (hb << 5);
            unsigned int packed = (unsigned int)f2bf(v0)
                                | ((unsigned int)f2bf(v1) << 16);
            unsigned int* dst = reinterpret_cast<unsigned int*>(If)
                + ((((unsigned)(1 - par)) * IF_FRAGS + (p * 128 + kt) * 64 + fl) * 8 + e) / 2;
            // coherent write-through to LLC (bypass non-coherent L2)
            asm volatile("global_store_dword %0, %1, off sc0 sc1"
                         :: "v"(dst), "v"(packed) : "memory");
        }

        // ---- p-group barrier (64 WGs), fence-free:
        // each WAVE drains its own stores to the coherent point, then arrive.
        asm volatile("s_waitcnt vmcnt(0)" ::: "memory");
        __syncthreads();
        if (tid == 0) {
            unsigned int* cp = ctr + ((unsigned)t * 4u + (unsigned)p) * 16u;
            __hip_atomic_fetch_add(cp, 1u, __ATOMIC_RELAXED, __HIP_MEMORY_SCOPE_AGENT);
            int guard = 0;
            while (__hip_atomic_load(cp, __ATOMIC_RELAXED, __HIP_MEMORY_SCOPE_AGENT) < 64u
                   && ++guard < (1 << 18)) {
                __builtin_amdgcn_s_sleep(1);
            }
        }
        __syncthreads();

        // ---- output contributions: fire-and-forget AFTER arrive (drained by
        // next step's vmcnt(0); never blocks the barrier).
        if ((tid & 15) == 0) {
            atomicAdd(out + (size_t)(b0 + eb) * TT + t, o0p);
            atomicAdd(out + (size_t)BB * TT + (size_t)(b0 + eb) * TT + t, o1p);
        }
    }
}

// ---------------------------------------------------------------------------
extern "C" void kernel_launch(void* const* d_in, const int* in_sizes, int n_in,
                              void* d_out, int out_size, void* d_ws, size_t ws_size,
                              hipStream_t stream)
{
    (void)in_sizes; (void)n_in; (void)ws_size;
    const float* x0    = (const float*)d_in[0];
    const float* x1    = (const float*)d_in[1];
    const float* enc0  = (const float*)d_in[2];
    const float* enc1  = (const float*)d_in[3];
    const float* dec0  = (const float*)d_in[4];
    const float* dec1  = (const float*)d_in[5];
    const float* W     = (const float*)d_in[6];
    const float* signs = (const float*)d_in[7];
    const float* mask  = (const float*)d_in[8];
    const float* st0   = (const float*)d_in[9];

    unsigned short* If  = (unsigned short*)((char*)d_ws + IF_OFF);
    unsigned int*   ctr = (unsigned int*)((char*)d_ws + CTR_OFF);
    float*          out = (float*)d_out;

    hipMemsetAsync(d_out, 0, sizeof(float) * (size_t)out_size, stream);
    hipMemsetAsync(ctr, 0, CTR_BYTES, stream);

    init_pack<<<1024, 256, 0, stream>>>(x0, x1, enc0, enc1, mask, st0, If);

    hipFuncSetAttribute(reinterpret_cast<const void*>(&dale_persistent),
                        hipFuncAttributeMaxDynamicSharedMemorySize, LDS_TOTAL);
    dale_persistent<<<256, 512, LDS_TOTAL, stream>>>(
        x0, x1, enc0, enc1, dec0, dec1, W, signs, mask, If, ctr, out);
}

// Round 3
// 6978.686 us; speedup vs baseline: 11.3645x; 1.0237x over previous
//
#include <hip/hip_runtime.h>
#include <hip/hip_bf16.h>
#include <stdint.h>

// ============================================================================
// DaleConstrainedIntegrator: s_t = mask*clip((s_{t-1}+mask*ext_t) @ Weff^T),
// o0/o1 = dec{0,1}·s_t.  N=2048, B=128, T=1024.
//
// R3 vs R2 (7.14 ms, MfmaUtil 6.3%): the 6.9us step was one serial chain
// ending in a 64-WG barrier. Restructured:
//  * Fine-grained sync: monotonic per-octet counters ctr[p][oct]. Producer WG
//    (p,q) arrives at ctr[p][q>>3]; consumer wave w polls ctr[p][w] >= 16*t
//    (2 finalist waves x 8 producer WGs per octet per step). A wave starts
//    its A-loads as soon as ITS 8 producers are done -- no global barrier.
//  * Short producer tail: 3-sync reduce tree (8->4->2 + half-exchange), then
//    waves 0,1 EACH finalize 16 batch rows: clip/mask, nsbuf write, DIRECT
//    ushort sc0/sc1 state stores (ext_{t+1} folded in), vmcnt(0), arrive.
//  * dec-dot output epilogue moved AFTER arrive (off critical path).
//  * A-loads: issue 16, vmcnt(8) -> MFMA 0-7 -> vmcnt(0) -> MFMA 8-15.
// WAR safety: parity double-buffer + arrivals happen only after the whole
// WG passed its A-load drains (reduce-tree syncs) => one step of slack
// suffices, same as the R2 proof.
// ============================================================================

#define NN 2048
#define BB 128
#define TT 1024

typedef __attribute__((ext_vector_type(8)))  __bf16          bf16x8;
typedef __attribute__((ext_vector_type(8)))  unsigned short  ushort8;
typedef __attribute__((ext_vector_type(16))) float           f32x16;

// ws layout (bytes)
#define IF_OFF   0u              // ushort I[2][4][128][64][8] = 1 MB
#define IF_FRAGS 32768           // bf16x8 frags per parity (4*128*64)
#define CTR_OFF  (1u << 20)      // uint ctr[4][8][16] (64B lines) = 2 KB
#define CTR_BYTES 2048u

__device__ __forceinline__ unsigned short f2bf(float f) {
    __hip_bfloat16 h = __float2bfloat16(f);
    return *reinterpret_cast<unsigned short*>(&h);
}

// ---------------------------------------------------------------------------
// Build I_0 = state0 + mask*(enc0*x0[:,0] + enc1*x1[:,0]), frag-packed.
// ---------------------------------------------------------------------------
__global__ void init_pack(const float* __restrict__ x0, const float* __restrict__ x1,
                          const float* __restrict__ enc0, const float* __restrict__ enc1,
                          const float* __restrict__ mask, const float* __restrict__ state0,
                          unsigned short* __restrict__ If)
{
    int idx  = blockIdx.x * 256 + threadIdx.x;        // 0 .. 262143
    int e    = idx & 7;
    int lane = (idx >> 3) & 63;
    int kt   = (idx >> 9) & 127;
    int p    = idx >> 16;
    int b    = p * 32 + (lane & 31);
    int j    = kt * 16 + ((lane >> 5) << 3) + e;
    float v  = state0[j] + mask[j] * (enc0[j] * x0[(size_t)b * TT]
                                    + enc1[j] * x1[(size_t)b * TT]);
    If[idx] = f2bf(v);
}

// ---------------------------------------------------------------------------
// Persistent recurrence kernel. LDS:
//   [0,128K)        Wl   : swizzled bf16 [32][2048]
//   [128K,+17408)   red  : float[4][64][17]
//   [..,+4352)      nsbuf: float[32][34]
//   [..,+768)       ldsC : float[6][32]  mask,dec0,dec1,enc0,enc1
//   [..,+256)       xbuf : float[2][32]
// total 153856 B
// ---------------------------------------------------------------------------
#define LDS_TOTAL 153856

__global__ void __launch_bounds__(512, 2)
dale_persistent(const float* __restrict__ x0, const float* __restrict__ x1,
                const float* __restrict__ enc0, const float* __restrict__ enc1,
                const float* __restrict__ dec0, const float* __restrict__ dec1,
                const float* __restrict__ W, const float* __restrict__ signs,
                const float* __restrict__ mask,
                unsigned short* __restrict__ If,
                unsigned int* __restrict__ ctr,
                float* __restrict__ out)
{
    extern __shared__ char lds[];
    float* red   = reinterpret_cast<float*>(lds + 131072);
    float* nsbuf = reinterpret_cast<float*>(lds + 131072 + 17408);
    float* ldsC  = reinterpret_cast<float*>(lds + 131072 + 17408 + 4352);
    float* xbuf  = reinterpret_cast<float*>(lds + 131072 + 17408 + 4352 + 768);

    const int tid  = threadIdx.x;
    const int wave = tid >> 6;
    const int lane = tid & 63;
    const int wg   = blockIdx.x;
    const int p  = (wg & 7) >> 1;                  // 0..3  batch chunk
    const int q  = ((wg & 1) << 5) | (wg >> 3);    // 0..63 neuron chunk
    const int b0 = p * 32;
    const int i0 = q * 32;

    // ---- one-time: Weff slice -> LDS (bf16, signs folded, slot-swizzled)
    for (int o = tid; o < 8192; o += 512) {
        int il8 = o >> 8;
        int k8  = o & 255;
        const float* wr = W + (size_t)(i0 + il8) * NN + k8 * 8;
        const float* sg = signs + k8 * 8;
        ushort8 pk;
        #pragma unroll
        for (int e = 0; e < 8; ++e) pk[e] = f2bf(wr[e] * sg[e]);
        int slot = k8 ^ il8;
        *reinterpret_cast<ushort8*>(lds + il8 * 4096 + slot * 16) = pk;
    }
    if (tid < 32) {
        ldsC[tid]       = mask[i0 + tid];
        ldsC[32 + tid]  = dec0[i0 + tid];
        ldsC[64 + tid]  = dec1[i0 + tid];
        ldsC[96 + tid]  = enc0[i0 + tid];
        ldsC[128 + tid] = enc1[i0 + tid];
    }
    __syncthreads();

    const int il = lane & 31;      // A row (batch) / B col's W-row (neuron)
    const int hi = lane >> 5;
    char* wrow = lds + il * 4096;

    // ---- hoisted per-thread constants
    const bf16x8* ApBase = reinterpret_cast<const bf16x8*>(If)
                         + (p * 128 + wave * 16) * 64 + lane;
    unsigned int* waitCtr = ctr + ((p * 8 + wave) << 4);
    unsigned int* arrCtr  = ctr + ((p * 8 + (q >> 3)) << 4);

    // finalize constants (used by waves 0,1; cheap for all)
    const float mk  = ldsC[il];
    const float e0c = ldsC[96 + il];
    const float e1c = ldsC[128 + il];
    const int jl   = i0 + il;
    const int kt_l = jl >> 4;
    const int hb_l = (jl >> 3) & 1;
    const int e_l  = jl & 7;
    unsigned short* sb0 = If + ((size_t)(p * 128 + kt_l) * 64) * 8 + e_l + hb_l * 256;
    unsigned short* sb1 = sb0 + (size_t)IF_FRAGS * 8;

    // epilogue constants
    const int eb = tid >> 4;
    const int ei = (tid & 15) * 2;
    const float d00 = ldsC[32 + ei], d01 = ldsC[32 + ei + 1];
    const float d10 = ldsC[64 + ei], d11 = ldsC[64 + ei + 1];
    float* out0 = out + (size_t)(b0 + eb) * TT;
    float* out1 = out + (size_t)BB * TT + (size_t)(b0 + eb) * TT;

    for (int t = 0; t < TT; ++t) {
        const int par = t & 1;

        // ---- wait for OUR octet's 8 producers (2 finalist arrivals each)
        if (t > 0) {
            const unsigned tgt = 16u * (unsigned)t;
            int guard = 0;
            for (;;) {
                unsigned vv = 0;
                if (lane == 0)
                    vv = __hip_atomic_load(waitCtr, __ATOMIC_RELAXED,
                                           __HIP_MEMORY_SCOPE_AGENT);
                unsigned v = (unsigned)__shfl((int)vv, 0, 64);
                if (v >= tgt || ++guard >= (1 << 17)) break;
                __builtin_amdgcn_s_sleep(1);
            }
        }

        // ---- x(t+1) prefetch into LDS (wave0 only; consumed by waves 0,1
        //      after reduce syncs)
        if (wave == 0) {
            int bb = lane & 31;
            const float* xs = (lane < 32) ? x0 : x1;
            float v = (t + 1 < TT) ? xs[(size_t)(b0 + bb) * TT + (t + 1)] : 0.f;
            xbuf[hi * 32 + bb] = v;
        }

        // ---- A-fragment loads (coherent, LLC-sourced)
        bf16x8 A[16];
        const bf16x8* ap = ApBase + (size_t)par * IF_FRAGS;
        #pragma unroll
        for (int it = 0; it < 16; ++it) {
            const bf16x8* aptr = ap + it * 64;
            asm volatile("global_load_dwordx4 %0, %1, off sc0 sc1"
                         : "=v"(A[it]) : "v"(aptr) : "memory");
        }

        f32x16 acc;
        #pragma unroll
        for (int r = 0; r < 16; ++r) acc[r] = 0.f;

        asm volatile("s_waitcnt vmcnt(8)" ::: "memory");
        __builtin_amdgcn_sched_barrier(0);
        #pragma unroll
        for (int it = 0; it < 8; ++it) {
            int kt   = wave * 16 + it;
            int slot = (kt * 2 + hi) ^ il;
            bf16x8 b = *reinterpret_cast<const bf16x8*>(wrow + slot * 16);
            acc = __builtin_amdgcn_mfma_f32_32x32x16_bf16(A[it], b, acc, 0, 0, 0);
        }
        asm volatile("s_waitcnt vmcnt(0)" ::: "memory");
        __builtin_amdgcn_sched_barrier(0);
        #pragma unroll
        for (int it = 8; it < 16; ++it) {
            int kt   = wave * 16 + it;
            int slot = (kt * 2 + hi) ^ il;
            bf16x8 b = *reinterpret_cast<const bf16x8*>(wrow + slot * 16);
            acc = __builtin_amdgcn_mfma_f32_32x32x16_bf16(A[it], b, acc, 0, 0, 0);
        }

        // ---- reduce: 8 -> 4 -> 2 (3 syncs), finalists = waves 0,1
        if (wave >= 4) {
            float* d = red + (wave - 4) * 1088 + lane * 17;
            #pragma unroll
            for (int r = 0; r < 16; ++r) d[r] = acc[r];
        }
        __syncthreads();                                   // sync1
        if (wave < 4) {
            const float* s = red + wave * 1088 + lane * 17;
            #pragma unroll
            for (int r = 0; r < 16; ++r) acc[r] += s[r];
            if (wave >= 2) {
                float* d = red + wave * 1088 + lane * 17;
                #pragma unroll
                for (int r = 0; r < 16; ++r) d[r] = acc[r];
            }
        }
        __syncthreads();                                   // sync2
        if (wave == 0) {
            const float* s = red + 2 * 1088 + lane * 17;
            #pragma unroll
            for (int r = 0; r < 16; ++r) acc[r] += s[r];
            float* d = red + lane * 17;                    // red[0] <- acc[8..16)
            #pragma unroll
            for (int rr = 0; rr < 8; ++rr) d[rr] = acc[8 + rr];
        } else if (wave == 1) {
            const float* s = red + 3 * 1088 + lane * 17;
            #pragma unroll
            for (int r = 0; r < 16; ++r) acc[r] += s[r];
            float* d = red + 1088 + lane * 17;             // red[1] <- acc[0..8)
            #pragma unroll
            for (int rr = 0; rr < 8; ++rr) d[rr] = acc[rr];
        }
        __syncthreads();                                   // sync3

        // ---- finalize: wave0 -> r 0..7 (brows 0..15), wave1 -> r 8..15
        if (wave < 2) {
            const float* s = red + (1 ^ wave) * 1088 + lane * 17;
            unsigned short* sb = (par == 0) ? sb1 : sb0;   // write parity 1-par
            #pragma unroll
            for (int rr = 0; rr < 8; ++rr) {
                int   r    = (wave << 3) + rr;
                float raw  = acc[r] + s[rr];
                int   brow = (r & 3) + 8 * (r >> 2) + 4 * hi;
                float ns   = fminf(fmaxf(raw, 0.f), 1e8f) * mk;
                nsbuf[brow * 34 + il] = ns;
                if (t + 1 < TT) {
                    float v = ns + mk * (e0c * xbuf[brow] + e1c * xbuf[32 + brow]);
                    unsigned int pv = (unsigned int)f2bf(v);
                    const unsigned short* dst = sb + brow * 8;
                    asm volatile("global_store_short %0, %1, off sc0 sc1"
                                 :: "v"(dst), "v"(pv) : "memory");
                }
            }
            if (t + 1 < TT) {
                asm volatile("s_waitcnt vmcnt(0)" ::: "memory");
                if (lane == 0)
                    __hip_atomic_fetch_add(arrCtr, 1u, __ATOMIC_RELAXED,
                                           __HIP_MEMORY_SCOPE_AGENT);
            }
        }
        __syncthreads();                                   // sync4 (nsbuf ready)

        // ---- output epilogue (off critical path, after arrive)
        {
            float ns0 = nsbuf[eb * 34 + ei];
            float ns1 = nsbuf[eb * 34 + ei + 1];
            float o0p = d00 * ns0 + d01 * ns1;
            float o1p = d10 * ns0 + d11 * ns1;
            #pragma unroll
            for (int m = 8; m >= 1; m >>= 1) {
                o0p += __shfl_xor(o0p, m);
                o1p += __shfl_xor(o1p, m);
            }
            if ((tid & 15) == 0) {
                atomicAdd(out0 + t, o0p);
                atomicAdd(out1 + t, o1p);
            }
        }
    }
}

// ---------------------------------------------------------------------------
extern "C" void kernel_launch(void* const* d_in, const int* in_sizes, int n_in,
                              void* d_out, int out_size, void* d_ws, size_t ws_size,
                              hipStream_t stream)
{
    (void)in_sizes; (void)n_in; (void)ws_size;
    const float* x0    = (const float*)d_in[0];
    const float* x1    = (const float*)d_in[1];
    const float* enc0  = (const float*)d_in[2];
    const float* enc1  = (const float*)d_in[3];
    const float* dec0  = (const float*)d_in[4];
    const float* dec1  = (const float*)d_in[5];
    const float* W     = (const float*)d_in[6];
    const float* signs = (const float*)d_in[7];
    const float* mask  = (const float*)d_in[8];
    const float* st0   = (const float*)d_in[9];

    unsigned short* If  = (unsigned short*)((char*)d_ws + IF_OFF);
    unsigned int*   ctr = (unsigned int*)((char*)d_ws + CTR_OFF);
    float*          out = (float*)d_out;

    hipMemsetAsync(d_out, 0, sizeof(float) * (size_t)out_size, stream);
    hipMemsetAsync(ctr, 0, CTR_BYTES, stream);

    init_pack<<<1024, 256, 0, stream>>>(x0, x1, enc0, enc1, mask, st0, If);

    hipFuncSetAttribute(reinterpret_cast<const void*>(&dale_persistent),
                        hipFuncAttributeMaxDynamicSharedMemorySize, LDS_TOTAL);
    dale_persistent<<<256, 512, LDS_TOTAL, stream>>>(
        x0, x1, enc0, enc1, dec0, dec1, W, signs, mask, If, ctr, out);
}